// Round 3
// baseline (2848.503 us; speedup 1.0000x reference)
//
#include <hip/hip_runtime.h>
#include <math.h>

#define CDIV(a,b) (((a)+(b)-1)/(b))
typedef unsigned int u32;

__device__ __forceinline__ float sigmoidf_(float x) { return 1.f / (1.f + __expf(-x)); }

template<int N>
__device__ __forceinline__ void load_vec(float* d, const float* s) {
    if constexpr (N % 4 == 0) {
        #pragma unroll
        for (int t = 0; t < N; t += 4) {
            float4 q = *reinterpret_cast<const float4*>(s + t);
            d[t] = q.x; d[t+1] = q.y; d[t+2] = q.z; d[t+3] = q.w;
        }
    } else if constexpr (N == 2) {
        float2 q = *reinterpret_cast<const float2*>(s);
        d[0] = q.x; d[1] = q.y;
    } else {
        #pragma unroll
        for (int t = 0; t < N; ++t) d[t] = s[t];
    }
}
template<int N>
__device__ __forceinline__ void store_vec(float* d, const float* s) {
    if constexpr (N % 4 == 0) {
        #pragma unroll
        for (int t = 0; t < N; t += 4)
            *reinterpret_cast<float4*>(d + t) = make_float4(s[t], s[t+1], s[t+2], s[t+3]);
    } else if constexpr (N == 2) {
        *reinterpret_cast<float2*>(d) = make_float2(s[0], s[1]);
    } else {
        #pragma unroll
        for (int t = 0; t < N; ++t) d[t] = s[t];
    }
}

// ---------------- mask dtype detection ----------------
__global__ void k_detect(const u32* __restrict__ w, int n, u32* __restrict__ flag) {
    u32 local = 0;
    for (int i = blockIdx.x * blockDim.x + threadIdx.x; i < n; i += gridDim.x * blockDim.x) {
        u32 v = w[i];
        if (v == 0x3F800000u) local |= 2u;
        else if (v > 1u)      local |= 1u;
    }
    if (local) atomicOr(flag, local);
}

__global__ void k_expand(const void* __restrict__ mraw, const u32* __restrict__ flag,
                         float* __restrict__ m, int n) {
    int i = blockIdx.x * blockDim.x + threadIdx.x;
    if (i >= n) return;
    u32 f = *flag;
    float v;
    if (f & 2u)      v = ((const float*)mraw)[i];
    else if (f & 1u) v = ((const unsigned char*)mraw)[i] ? 1.f : 0.f;
    else             v = ((const int*)mraw)[i] ? 1.f : 0.f;
    m[i] = v;
}

// ---------------- mask max-pool 2x2x2 + count ----------------
__global__ void k_pool(const float* __restrict__ mi, float* __restrict__ mo,
                       float* __restrict__ cnt, int Si, int n) {
    int So = Si >> 1;
    int i = blockIdx.x * blockDim.x + threadIdx.x;
    float v = 0.f;
    if (i < n) {
        int x = i % So; int t = i / So;
        int y = t % So; t /= So;
        int z = t % So; int b = t / So;
        const float* p = mi + (size_t)b * Si * Si * Si;
        #pragma unroll
        for (int dz = 0; dz < 2; dz++)
        #pragma unroll
        for (int dy = 0; dy < 2; dy++)
        #pragma unroll
        for (int dx = 0; dx < 2; dx++) {
            float q = p[((size_t)(2 * z + dz) * Si + (2 * y + dy)) * Si + (2 * x + dx)];
            v = fmaxf(v, q);
        }
        mo[i] = v;
    }
    __shared__ float red[256];
    red[threadIdx.x] = v; __syncthreads();
    for (int s = 128; s > 0; s >>= 1) {
        if (threadIdx.x < s) red[threadIdx.x] += red[threadIdx.x + s];
        __syncthreads();
    }
    if (threadIdx.x == 0) atomicAdd(cnt, red[0]);
}

// ---------------- strided conv 3x3x3 s2 p1, one output voxel x CO_T per thread ----
// Row-outer / ci-inner; mask hoisted per row. STATS: fused masked BN partial sums
// (requires exact grid fit: SOUT3 % 256 == 0 and CI_SPLIT == 1).
template<int CI, int CO, int CO_T, int SIN, int SOUT, bool MASK_IN, int CI_SPLIT, bool STATS>
__global__ __launch_bounds__(256, 2)
void k_conv(const float* __restrict__ in, const float* __restrict__ inm,
            const float* __restrict__ W, float* __restrict__ out,
            const float* __restrict__ mout, float* __restrict__ stats) {
    constexpr int SIN3 = SIN * SIN * SIN;
    constexpr int SOUT3 = SOUT * SOUT * SOUT;
    constexpr int CIL = CI / CI_SPLIT;
    constexpr int NW = 27 * CIL * CO_T;
    constexpr bool ATOMIC = (CI_SPLIT > 1);
    __shared__ __align__(16) float wlds[NW];
    __shared__ float sred[STATS ? 4 : 1][2 * CO_T];
    const int cog = blockIdx.y / CI_SPLIT;
    const int cs  = blockIdx.y % CI_SPLIT;
    const int cobase = cog * CO_T;
    const int cibase = cs * CIL;
    const int b = blockIdx.z;
    for (int idx = threadIdx.x; idx < NW; idx += 256) {
        int w   = idx / (CIL * CO_T);
        int rem = idx - w * (CIL * CO_T);
        int ci  = rem / CO_T;
        int co  = rem - ci * CO_T;
        wlds[idx] = W[(size_t)(w * CI + cibase + ci) * CO + cobase + co];
    }
    __syncthreads();
    int chunk = blockIdx.x * 256 + threadIdx.x;
    bool active = chunk < SOUT3;
    if (!STATS && !active) return;

    float acc[CO_T];
    #pragma unroll
    for (int co = 0; co < CO_T; ++co) acc[co] = 0.f;

    if (active) {
        int x = chunk % SOUT; int r = chunk / SOUT;
        int y = r % SOUT, z = r / SOUT;
        const float* bi = in + (size_t)(b * CI + cibase) * SIN3;
        const float* bm = MASK_IN ? (inm + (size_t)b * SIN3) : nullptr;
        const int xbase = 2 * x - 1;
        #pragma unroll
        for (int kz = 0; kz < 3; ++kz) {
            int iz = 2 * z - 1 + kz;
            #pragma unroll
            for (int ky = 0; ky < 3; ++ky) {
                int iy = 2 * y - 1 + ky;
                bool rv = (iz >= 0) && (iy >= 0);
                int rowoff = (iz * SIN + iy) * SIN;
                float mv0 = 1.f, mv1 = 1.f, mv2 = 1.f;
                if (MASK_IN) {
                    mv0 = (rv && xbase >= 0) ? bm[rowoff + xbase] : 0.f;
                    mv1 = rv ? bm[rowoff + xbase + 1] : 0.f;
                    mv2 = rv ? bm[rowoff + xbase + 2] : 0.f;
                }
                const float* wrow = &wlds[(kz * 3 + ky) * 3 * CIL * CO_T];
                #pragma unroll
                for (int ci = 0; ci < CIL; ++ci) {
                    const float* rp = bi + (size_t)ci * SIN3 + rowoff;
                    float v0 = (rv && xbase >= 0) ? rp[xbase] : 0.f;
                    float v1 = rv ? rp[xbase + 1] : 0.f;
                    float v2 = rv ? rp[xbase + 2] : 0.f;
                    if (MASK_IN) { v0 *= mv0; v1 *= mv1; v2 *= mv2; }
                    const float* wp = wrow + ci * CO_T;
                    #pragma unroll
                    for (int co = 0; co < CO_T; ++co) acc[co] += v0 * wp[co];
                    #pragma unroll
                    for (int co = 0; co < CO_T; ++co) acc[co] += v1 * wp[CIL * CO_T + co];
                    #pragma unroll
                    for (int co = 0; co < CO_T; ++co) acc[co] += v2 * wp[2 * CIL * CO_T + co];
                }
            }
        }
        #pragma unroll
        for (int co = 0; co < CO_T; ++co) {
            float* op = out + (size_t)(b * CO + cobase + co) * SOUT3 + chunk;
            if constexpr (ATOMIC) atomicAdd(op, acc[co]); else *op = acc[co];
        }
    }

    if constexpr (STATS) {
        float mm = active ? mout[(size_t)b * SOUT3 + chunk] : 0.f;
        float s1[CO_T], s2[CO_T];
        #pragma unroll
        for (int co = 0; co < CO_T; ++co) { float v = acc[co] * mm; s1[co] = v; s2[co] = acc[co] * v; }
        #pragma unroll
        for (int co = 0; co < CO_T; ++co)
            for (int off = 1; off < 64; off <<= 1) {
                s1[co] += __shfl_xor(s1[co], off);
                s2[co] += __shfl_xor(s2[co], off);
            }
        int lane = threadIdx.x & 63, wid = threadIdx.x >> 6;
        if (lane == 0) {
            #pragma unroll
            for (int co = 0; co < CO_T; ++co) { sred[wid][co] = s1[co]; sred[wid][CO_T + co] = s2[co]; }
        }
        __syncthreads();
        if (threadIdx.x < 2 * CO_T) {
            int t = threadIdx.x;
            float v = sred[0][t] + sred[1][t] + sred[2][t] + sred[3][t];
            int addr = (t < CO_T) ? (cobase + t) : (128 + cobase + (t - CO_T));
            atomicAdd(&stats[addr], v);
        }
    }
}

// ---------------- blocked transposed conv 3x3x3 s2 ----------------
template<int CI, int CO, int CO_T, int CO_P, int SP_T, int SIN, bool FINAL, int CI_SPLIT, bool STATS>
__global__ __launch_bounds__(256, 2)
void k_deconv(const float* __restrict__ in, const float* __restrict__ W,
              const float* __restrict__ mout, float* __restrict__ out,
              const float* __restrict__ occw, const float* __restrict__ occb,
              float* __restrict__ occout, float* __restrict__ stats) {
    constexpr int SOUT = 2 * SIN;
    constexpr int SIN3 = SIN * SIN * SIN;
    constexpr int SOUT3 = SOUT * SOUT * SOUT;
    constexpr int CIL = CI / CI_SPLIT;
    constexpr int NW = 27 * CIL * CO_P;
    constexpr bool ATOMIC = (CI_SPLIT > 1);
    __shared__ __align__(16) float wlds[NW];
    __shared__ float sred[STATS ? 4 : 1][2 * CO_T];
    const int cog = blockIdx.y / CI_SPLIT;
    const int cs  = blockIdx.y % CI_SPLIT;
    const int cobase = cog * CO_T;
    const int cibase = cs * CIL;
    const int b = blockIdx.z;
    for (int idx = threadIdx.x; idx < NW; idx += 256) {
        int w   = idx / (CIL * CO_P);
        int rem = idx - w * (CIL * CO_P);
        int ci  = rem / CO_P;
        int co  = rem - ci * CO_P;
        wlds[idx] = (co < CO_T) ? W[(size_t)(w * CI + cibase + ci) * CO + cobase + co] : 0.f;
    }
    __syncthreads();
    constexpr int KCH = SIN / SP_T;
    int chunk = blockIdx.x * 256 + threadIdx.x;
    bool active = chunk < SIN * SIN * KCH;
    if (!STATS && !active) return;
    int k0 = 0, j = 0, i = 0;
    if (active) {
        k0 = (chunk % KCH) * SP_T;
        int r = chunk / KCH;
        j = r % SIN; i = r / SIN;
    }

    float acc[2][2][2 * SP_T][CO_T];
    #pragma unroll
    for (int pz = 0; pz < 2; ++pz)
    #pragma unroll
    for (int py = 0; py < 2; ++py)
    #pragma unroll
    for (int ox = 0; ox < 2 * SP_T; ++ox)
    #pragma unroll
    for (int co = 0; co < CO_T; ++co) acc[pz][py][ox][co] = 0.f;

    constexpr int PPa[3] = {1, 0, 1};   // weight idx -> output parity
    constexpr int DDa[3] = {1, 0, 0};   // weight idx -> input offset

    if (active) {
        #pragma unroll 1
        for (int ci = 0; ci < CIL; ++ci) {
            const float* bi = in + (size_t)(b * CI + cibase + ci) * SIN3;
            float v[2][2][SP_T + 1];
            #pragma unroll
            for (int dz = 0; dz < 2; ++dz)
            #pragma unroll
            for (int dy = 0; dy < 2; ++dy) {
                int zi = i + dz, yj = j + dy;
                bool rv = (zi < SIN) && (yj < SIN);
                const float* rp = bi + (zi * SIN + yj) * SIN + k0;
                #pragma unroll
                for (int t = 0; t <= SP_T; ++t)
                    v[dz][dy][t] = (rv && (k0 + t < SIN)) ? rp[t] : 0.f;
            }
            #pragma unroll
            for (int w = 0; w < 27; ++w) {
                const int wz = w / 9, wy = (w / 3) % 3, wx = w % 3;
                float wv[CO_P];
                load_vec<CO_P>(wv, &wlds[(w * CIL + ci) * CO_P]);
                #pragma unroll
                for (int sp = 0; sp < SP_T; ++sp) {
                    float iv = v[DDa[wz]][DDa[wy]][sp + DDa[wx]];
                    #pragma unroll
                    for (int co = 0; co < CO_T; ++co)
                        acc[PPa[wz]][PPa[wy]][2 * sp + PPa[wx]][co] += iv * wv[co];
                }
            }
        }
    }

    if constexpr (!FINAL) {
        if (active) {
            #pragma unroll
            for (int co = 0; co < CO_T; ++co)
            #pragma unroll
            for (int pz = 0; pz < 2; ++pz)
            #pragma unroll
            for (int py = 0; py < 2; ++py) {
                float* op = out + (size_t)(b * CO + cobase + co) * SOUT3
                          + ((2 * i + pz) * SOUT + (2 * j + py)) * SOUT + 2 * k0;
                if constexpr (ATOMIC) {
                    #pragma unroll
                    for (int ox = 0; ox < 2 * SP_T; ++ox) atomicAdd(op + ox, acc[pz][py][ox][co]);
                } else {
                    float tmp[2 * SP_T];
                    #pragma unroll
                    for (int ox = 0; ox < 2 * SP_T; ++ox) tmp[ox] = acc[pz][py][ox][co];
                    store_vec<2 * SP_T>(op, tmp);
                }
            }
        }
        if constexpr (STATS) {
            float mm[2][2][2 * SP_T];
            #pragma unroll
            for (int pz = 0; pz < 2; ++pz)
            #pragma unroll
            for (int py = 0; py < 2; ++py) {
                if (active) {
                    load_vec<2 * SP_T>(&mm[pz][py][0],
                        mout + (size_t)b * SOUT3 + ((2 * i + pz) * SOUT + (2 * j + py)) * SOUT + 2 * k0);
                } else {
                    #pragma unroll
                    for (int ox = 0; ox < 2 * SP_T; ++ox) mm[pz][py][ox] = 0.f;
                }
            }
            float s1[CO_T], s2[CO_T];
            #pragma unroll
            for (int co = 0; co < CO_T; ++co) {
                float a1 = 0.f, a2 = 0.f;
                #pragma unroll
                for (int pz = 0; pz < 2; ++pz)
                #pragma unroll
                for (int py = 0; py < 2; ++py)
                #pragma unroll
                for (int ox = 0; ox < 2 * SP_T; ++ox) {
                    float av = acc[pz][py][ox][co], mv = mm[pz][py][ox];
                    a1 += av * mv; a2 += av * av * mv;
                }
                s1[co] = a1; s2[co] = a2;
            }
            #pragma unroll
            for (int co = 0; co < CO_T; ++co)
                for (int off = 1; off < 64; off <<= 1) {
                    s1[co] += __shfl_xor(s1[co], off);
                    s2[co] += __shfl_xor(s2[co], off);
                }
            int lane = threadIdx.x & 63, wid = threadIdx.x >> 6;
            if (lane == 0) {
                #pragma unroll
                for (int co = 0; co < CO_T; ++co) { sred[wid][co] = s1[co]; sred[wid][CO_T + co] = s2[co]; }
            }
            __syncthreads();
            if (threadIdx.x < 2 * CO_T) {
                int t = threadIdx.x;
                float v = sred[0][t] + sred[1][t] + sred[2][t] + sred[3][t];
                int addr = (t < CO_T) ? (cobase + t) : (128 + cobase + (t - CO_T));
                atomicAdd(&stats[addr], v);
            }
        }
    } else {
        const float w0 = occw[0], w1 = occw[1], w2 = occw[2], bo = occb[0];
        #pragma unroll
        for (int pz = 0; pz < 2; ++pz)
        #pragma unroll
        for (int py = 0; py < 2; ++py) {
            const int row = ((2 * i + pz) * SOUT + (2 * j + py)) * SOUT + 2 * k0;
            float mm[2 * SP_T];
            load_vec<2 * SP_T>(mm, mout + (size_t)b * SOUT3 + row);
            float d0[3][2 * SP_T];
            float p1[2 * SP_T];
            #pragma unroll
            for (int ox = 0; ox < 2 * SP_T; ++ox) {
                float y0 = sigmoidf_(acc[pz][py][ox][0]) * mm[ox];
                float y1 = sigmoidf_(acc[pz][py][ox][1]) * mm[ox];
                float y2 = sigmoidf_(acc[pz][py][ox][2]) * mm[ox];
                d0[0][ox] = y0; d0[1][ox] = y1; d0[2][ox] = y2;
                p1[ox] = sigmoidf_(y0 * w0 + y1 * w1 + y2 * w2 + bo) * mm[ox];
            }
            #pragma unroll
            for (int co = 0; co < 3; ++co)
                store_vec<2 * SP_T>(out + (size_t)(b * 3 + co) * SOUT3 + row, d0[co]);
            store_vec<2 * SP_T>(occout + (size_t)b * SOUT3 + row, p1);
        }
    }
}

// ---------------- masked BN statistics (small levels only) ----------------
__global__ void k_stats(const float* __restrict__ x, const float* __restrict__ m,
                        int C, int S3, int NB, float* __restrict__ stats) {
    int c = blockIdx.y;
    float s1 = 0.f, s2 = 0.f;
    int tid = blockIdx.x * blockDim.x + threadIdx.x;
    int stride = gridDim.x * blockDim.x;
    for (int b = 0; b < NB; b++) {
        const float* xb = x + ((size_t)b * C + c) * S3;
        const float* mb = m + (size_t)b * S3;
        for (int i = tid; i < S3; i += stride) {
            float v = xb[i] * mb[i];
            s1 += v; s2 += v * v;
        }
    }
    __shared__ float r1[256], r2[256];
    r1[threadIdx.x] = s1; r2[threadIdx.x] = s2; __syncthreads();
    for (int s = 128; s > 0; s >>= 1) {
        if (threadIdx.x < s) { r1[threadIdx.x] += r1[threadIdx.x + s]; r2[threadIdx.x] += r2[threadIdx.x + s]; }
        __syncthreads();
    }
    if (threadIdx.x == 0) { atomicAdd(&stats[c], r1[0]); atomicAdd(&stats[128 + c], r2[0]); }
}

// scale/shift: st[256+c]=gamma*rsqrt(var+eps), st[384+c]=beta-mean*scale
__global__ void k_finalize(float* __restrict__ st, const float* __restrict__ cnt,
                           const float* __restrict__ g, const float* __restrict__ be, int C) {
    int c = threadIdx.x;
    if (c < C) {
        float cn = *cnt;
        float mean = st[c] / cn;
        float var = st[128 + c] / cn - mean * mean;
        float sc = g[c] * rsqrtf(var + 1e-5f);
        st[256 + c] = sc;
        st[384 + c] = be[c] - mean * sc;
    }
}

// ---------------- BN apply + ReLU + mask (+ occ head, + skip add), float4 ------
template<int C, int S3, bool OCC, bool ADD>
__global__ __launch_bounds__(256)
void k_bn(float* __restrict__ x, const float* __restrict__ m,
          const float* __restrict__ st, const float* __restrict__ skip,
          const float* __restrict__ ow, const float* __restrict__ ob,
          float* __restrict__ oo, int nq) {
    int idx = blockIdx.x * 256 + threadIdx.x;
    if (idx >= nq) return;
    constexpr int SQ = S3 / 4;
    int b = idx / SQ;
    int sp = (idx - b * SQ) * 4;
    float4 mm = *reinterpret_cast<const float4*>(m + (size_t)b * S3 + sp);
    float o0 = 0.f, o1 = 0.f, o2 = 0.f, o3 = 0.f;
    #pragma unroll 4
    for (int c = 0; c < C; ++c) {
        size_t off = (size_t)(b * C + c) * S3 + sp;
        float4 xv = *reinterpret_cast<const float4*>(x + off);
        float sc = st[256 + c], sh = st[384 + c];
        float y0 = fmaxf(xv.x * sc + sh, 0.f) * mm.x;
        float y1 = fmaxf(xv.y * sc + sh, 0.f) * mm.y;
        float y2 = fmaxf(xv.z * sc + sh, 0.f) * mm.z;
        float y3 = fmaxf(xv.w * sc + sh, 0.f) * mm.w;
        if (OCC) { float wv = ow[c]; o0 += y0 * wv; o1 += y1 * wv; o2 += y2 * wv; o3 += y3 * wv; }
        if (ADD) {
            float4 sk = *reinterpret_cast<const float4*>(skip + off);
            y0 += sk.x; y1 += sk.y; y2 += sk.z; y3 += sk.w;
        }
        *reinterpret_cast<float4*>(x + off) = make_float4(y0, y1, y2, y3);
    }
    if (OCC) {
        float bb = ob[0];
        *reinterpret_cast<float4*>(oo + (size_t)b * S3 + sp) =
            make_float4(sigmoidf_(o0 + bb) * mm.x, sigmoidf_(o1 + bb) * mm.y,
                        sigmoidf_(o2 + bb) * mm.z, sigmoidf_(o3 + bb) * mm.w);
    }
}

// ---------------- launch ----------------
extern "C" void kernel_launch(void* const* d_in, const int* in_sizes, int n_in,
                              void* d_out, int out_size, void* d_ws, size_t ws_size,
                              hipStream_t stream) {
    (void)in_sizes; (void)n_in; (void)out_size; (void)ws_size;
    const float* feats = (const float*)d_in[0];
    const void*  mraw  = d_in[1];
    const float* W1 = (const float*)d_in[2];
    const float* g1 = (const float*)d_in[3];  const float* b1 = (const float*)d_in[4];
    const float* W2 = (const float*)d_in[5];
    const float* g2 = (const float*)d_in[6];  const float* b2 = (const float*)d_in[7];
    const float* W3 = (const float*)d_in[8];
    const float* g3 = (const float*)d_in[9];  const float* b3 = (const float*)d_in[10];
    const float* W4 = (const float*)d_in[11];
    const float* g4 = (const float*)d_in[12]; const float* b4 = (const float*)d_in[13];
    const float* Wt4 = (const float*)d_in[14];
    const float* gd4 = (const float*)d_in[15]; const float* bd4 = (const float*)d_in[16];
    const float* wo4 = (const float*)d_in[17]; const float* bo4 = (const float*)d_in[18];
    const float* Wt3 = (const float*)d_in[19];
    const float* gd3 = (const float*)d_in[20]; const float* bd3 = (const float*)d_in[21];
    const float* wo3 = (const float*)d_in[22]; const float* bo3 = (const float*)d_in[23];
    const float* Wt2 = (const float*)d_in[24];
    const float* gd2 = (const float*)d_in[25]; const float* bd2 = (const float*)d_in[26];
    const float* wo2 = (const float*)d_in[27]; const float* bo2 = (const float*)d_in[28];
    const float* Wt1 = (const float*)d_in[29];
    const float* wo1 = (const float*)d_in[30]; const float* bo1 = (const float*)d_in[31];

    float* out = (float*)d_out;

    const int NB = 2;
    const int V0 = 96 * 96 * 96;
    const int V1 = 48 * 48 * 48;
    const int V2 = 24 * 24 * 24;
    const int V3 = 12 * 12 * 12;
    const int V4 = 6 * 6 * 6;

    const size_t OFF_P4 = (size_t)NB * 3 * V0;
    const size_t OFF_P3 = OFF_P4 + (size_t)NB * V3;
    const size_t OFF_P2 = OFF_P3 + (size_t)NB * V2;
    const size_t OFF_P1 = OFF_P2 + (size_t)NB * V1;

    float* ws = (float*)d_ws;
    size_t o = 0;
    auto alloc = [&](size_t n) { float* p = ws + o; o += ((n + 63) / 64) * 64; return p; };
    u32*   flag  = (u32*)alloc(64);
    float* m0f   = alloc((size_t)NB * V0);
    float* m1f   = alloc((size_t)NB * V1);
    float* m2f   = alloc((size_t)NB * V2);
    float* m3f   = alloc((size_t)NB * V3);
    float* m4f   = alloc((size_t)NB * V4);
    float* cnt   = alloc(16);
    float* stats = alloc(8 * 512);
    float* e0    = alloc((size_t)NB * 16 * V1);
    float* e1    = alloc((size_t)NB * 32 * V2);
    float* e2    = alloc((size_t)NB * 64 * V3);
    float* e3    = alloc((size_t)NB * 128 * V4);
    float* d3    = alloc((size_t)NB * 64 * V3);
    float* d2    = alloc((size_t)NB * 32 * V2);
    float* d1    = alloc((size_t)NB * 16 * V1);
    (void)alloc(140000);   // guard slack

    const int T = 256;

    hipMemsetAsync(flag, 0, 256, stream);
    hipMemsetAsync(cnt, 0, 64, stream);
    hipMemsetAsync(stats, 0, 8 * 512 * sizeof(float), stream);
    // zero targets of atomic (CI-split) conv/deconv
    hipMemsetAsync(e2, 0, (size_t)NB * 64 * V3 * sizeof(float), stream);
    hipMemsetAsync(e3, 0, (size_t)NB * 128 * V4 * sizeof(float), stream);
    hipMemsetAsync(d3, 0, (size_t)NB * 64 * V3 * sizeof(float), stream);
    hipMemsetAsync(d2, 0, (size_t)NB * 32 * V2 * sizeof(float), stream);

    // masks
    k_detect<<<256, T, 0, stream>>>((const u32*)mraw, (NB * V0) / 4, flag);
    k_expand<<<CDIV(NB * V0, T), T, 0, stream>>>(mraw, flag, m0f, NB * V0);
    k_pool<<<CDIV(NB * V1, T), T, 0, stream>>>(m0f, m1f, &cnt[0], 96, NB * V1);
    k_pool<<<CDIV(NB * V2, T), T, 0, stream>>>(m1f, m2f, &cnt[1], 48, NB * V2);
    k_pool<<<CDIV(NB * V3, T), T, 0, stream>>>(m2f, m3f, &cnt[2], 24, NB * V3);
    k_pool<<<CDIV(NB * V4, T), T, 0, stream>>>(m3f, m4f, &cnt[3], 12, NB * V4);

    // ---- encoder ----
    // conv1: 96->48, 3->16, CO_T=16, exact fit 432*256 = 110592, stats fused
    k_conv<3, 16, 16, 96, 48, true, 1, true><<<dim3(432, 1, 2), T, 0, stream>>>(
        feats, m0f, W1, e0, m1f, stats + 0 * 512);
    k_finalize<<<1, 128, 0, stream>>>(stats + 0 * 512, &cnt[0], g1, b1, 16);
    k_bn<16, 110592, false, false><<<CDIV(NB * V1 / 4, T), T, 0, stream>>>(
        e0, m1f, stats + 0 * 512, nullptr, nullptr, nullptr, nullptr, NB * V1 / 4);

    // conv2: 48->24, 16->32, CO_T=4 (8 groups), exact fit 54*256 = 13824, stats fused
    k_conv<16, 32, 4, 48, 24, false, 1, true><<<dim3(54, 8, 2), T, 0, stream>>>(
        e0, nullptr, W2, e1, m2f, stats + 1 * 512);
    k_finalize<<<1, 128, 0, stream>>>(stats + 1 * 512, &cnt[1], g2, b2, 32);
    k_bn<32, 13824, false, false><<<CDIV(NB * V2 / 4, T), T, 0, stream>>>(
        e1, m2f, stats + 1 * 512, nullptr, nullptr, nullptr, nullptr, NB * V2 / 4);

    // conv3: 24->12, 32->64, CO_T=4 x CI_SPLIT=2
    k_conv<32, 64, 4, 24, 12, false, 2, false><<<dim3(7, 32, 2), T, 0, stream>>>(
        e1, nullptr, W3, e2, nullptr, nullptr);
    k_stats<<<dim3(4, 64), T, 0, stream>>>(e2, m3f, 64, V3, NB, stats + 2 * 512);
    k_finalize<<<1, 128, 0, stream>>>(stats + 2 * 512, &cnt[2], g3, b3, 64);
    k_bn<64, 1728, false, false><<<CDIV(NB * V3 / 4, T), T, 0, stream>>>(
        e2, m3f, stats + 2 * 512, nullptr, nullptr, nullptr, nullptr, NB * V3 / 4);

    // conv4: 12->6, 64->128, CO_T=4 x CI_SPLIT=8
    k_conv<64, 128, 4, 12, 6, false, 8, false><<<dim3(1, 256, 2), T, 0, stream>>>(
        e2, nullptr, W4, e3, nullptr, nullptr);
    k_stats<<<dim3(1, 128), T, 0, stream>>>(e3, m4f, 128, V4, NB, stats + 3 * 512);
    k_finalize<<<1, 128, 0, stream>>>(stats + 3 * 512, &cnt[3], g4, b4, 128);
    k_bn<128, 216, false, false><<<CDIV(NB * V4 / 4, T), T, 0, stream>>>(
        e3, m4f, stats + 3 * 512, nullptr, nullptr, nullptr, nullptr, NB * V4 / 4);

    // ---- decoder 4 -> 3 ----
    k_deconv<128, 64, 4, 4, 1, 6, false, 8, false><<<dim3(1, 128, 2), T, 0, stream>>>(
        e3, Wt4, nullptr, d3, nullptr, nullptr, nullptr, nullptr);
    k_stats<<<dim3(4, 64), T, 0, stream>>>(d3, m3f, 64, V3, NB, stats + 4 * 512);
    k_finalize<<<1, 128, 0, stream>>>(stats + 4 * 512, &cnt[2], gd4, bd4, 64);
    k_bn<64, 1728, true, true><<<CDIV(NB * V3 / 4, T), T, 0, stream>>>(
        d3, m3f, stats + 4 * 512, e2, wo4, bo4, out + OFF_P4, NB * V3 / 4);

    // ---- decoder 3 -> 2 ----
    k_deconv<64, 32, 4, 4, 1, 12, false, 4, false><<<dim3(7, 32, 2), T, 0, stream>>>(
        d3, Wt3, nullptr, d2, nullptr, nullptr, nullptr, nullptr);
    k_stats<<<dim3(16, 32), T, 0, stream>>>(d2, m2f, 32, V2, NB, stats + 5 * 512);
    k_finalize<<<1, 128, 0, stream>>>(stats + 5 * 512, &cnt[1], gd3, bd3, 32);
    k_bn<32, 13824, true, true><<<CDIV(NB * V2 / 4, T), T, 0, stream>>>(
        d2, m2f, stats + 5 * 512, e1, wo3, bo3, out + OFF_P3, NB * V2 / 4);

    // ---- decoder 2 -> 1 ---- exact fit 54*256=13824, stats fused
    k_deconv<32, 16, 4, 4, 1, 24, false, 1, true><<<dim3(54, 4, 2), T, 0, stream>>>(
        d2, Wt2, m1f, d1, nullptr, nullptr, nullptr, stats + 6 * 512);
    k_finalize<<<1, 128, 0, stream>>>(stats + 6 * 512, &cnt[0], gd2, bd2, 16);
    k_bn<16, 110592, true, true><<<CDIV(NB * V1 / 4, T), T, 0, stream>>>(
        d1, m1f, stats + 6 * 512, e0, wo2, bo2, out + OFF_P2, NB * V1 / 4);

    // ---- final level 1 -> 0: d0 + p1 fused ---- exact fit 216*256=55296
    k_deconv<16, 3, 3, 4, 2, 48, true, 1, false><<<dim3(216, 1, 2), T, 0, stream>>>(
        d1, Wt1, m0f, out, wo1, bo1, out + OFF_P1, nullptr);
}

// Round 4
// 582.256 us; speedup vs baseline: 4.8922x; 4.8922x over previous
//
#include <hip/hip_runtime.h>
#include <math.h>

#define CDIV(a,b) (((a)+(b)-1)/(b))
typedef unsigned int u32;

__device__ __forceinline__ float sigmoidf_(float x) { return 1.f / (1.f + __expf(-x)); }

template<int N>
__device__ __forceinline__ void load_vec(float* d, const float* s) {
    if constexpr (N % 4 == 0) {
        #pragma unroll
        for (int t = 0; t < N; t += 4) {
            float4 q = *reinterpret_cast<const float4*>(s + t);
            d[t] = q.x; d[t+1] = q.y; d[t+2] = q.z; d[t+3] = q.w;
        }
    } else if constexpr (N == 2) {
        float2 q = *reinterpret_cast<const float2*>(s);
        d[0] = q.x; d[1] = q.y;
    } else {
        #pragma unroll
        for (int t = 0; t < N; ++t) d[t] = s[t];
    }
}
template<int N>
__device__ __forceinline__ void store_vec(float* d, const float* s) {
    if constexpr (N % 4 == 0) {
        #pragma unroll
        for (int t = 0; t < N; t += 4)
            *reinterpret_cast<float4*>(d + t) = make_float4(s[t], s[t+1], s[t+2], s[t+3]);
    } else if constexpr (N == 2) {
        *reinterpret_cast<float2*>(d) = make_float2(s[0], s[1]);
    } else {
        #pragma unroll
        for (int t = 0; t < N; ++t) d[t] = s[t];
    }
}

// ---------------- mask dtype detection ----------------
__global__ void k_detect(const u32* __restrict__ w, int n, u32* __restrict__ flag) {
    u32 local = 0;
    for (int i = blockIdx.x * blockDim.x + threadIdx.x; i < n; i += gridDim.x * blockDim.x) {
        u32 v = w[i];
        if (v == 0x3F800000u) local |= 2u;
        else if (v > 1u)      local |= 1u;
    }
    if (local) atomicOr(flag, local);
}

__global__ void k_expand(const void* __restrict__ mraw, const u32* __restrict__ flag,
                         float* __restrict__ m, int n) {
    int i = blockIdx.x * blockDim.x + threadIdx.x;
    if (i >= n) return;
    u32 f = *flag;
    float v;
    if (f & 2u)      v = ((const float*)mraw)[i];
    else if (f & 1u) v = ((const unsigned char*)mraw)[i] ? 1.f : 0.f;
    else             v = ((const int*)mraw)[i] ? 1.f : 0.f;
    m[i] = v;
}

// ---------------- mask max-pool 2x2x2 + count ----------------
__global__ void k_pool(const float* __restrict__ mi, float* __restrict__ mo,
                       float* __restrict__ cnt, int Si, int n) {
    int So = Si >> 1;
    int i = blockIdx.x * blockDim.x + threadIdx.x;
    float v = 0.f;
    if (i < n) {
        int x = i % So; int t = i / So;
        int y = t % So; t /= So;
        int z = t % So; int b = t / So;
        const float* p = mi + (size_t)b * Si * Si * Si;
        #pragma unroll
        for (int dz = 0; dz < 2; dz++)
        #pragma unroll
        for (int dy = 0; dy < 2; dy++)
        #pragma unroll
        for (int dx = 0; dx < 2; dx++) {
            float q = p[((size_t)(2 * z + dz) * Si + (2 * y + dy)) * Si + (2 * x + dx)];
            v = fmaxf(v, q);
        }
        mo[i] = v;
    }
    __shared__ float red[256];
    red[threadIdx.x] = v; __syncthreads();
    for (int s = 128; s > 0; s >>= 1) {
        if (threadIdx.x < s) red[threadIdx.x] += red[threadIdx.x + s];
        __syncthreads();
    }
    if (threadIdx.x == 0) atomicAdd(cnt, red[0]);
}

// ---------------- blocked strided conv 3x3x3 s2 p1, output GATED by mout ------
// thread: (b, co-group, z, y, x0..x0+SP_T-1). Weights in LDS (broadcast).
// Rows outer, ci inner (mask row hoisted). Gating distributes over CI splits.
template<int CI, int CO, int CO_T, int SP_T, int SIN, int SOUT, bool MASK_IN, int CI_SPLIT>
__global__ __launch_bounds__(256)
void k_conv(const float* __restrict__ in, const float* __restrict__ inm,
            const float* __restrict__ W, float* __restrict__ out,
            const float* __restrict__ mout) {
    constexpr int SIN3 = SIN * SIN * SIN;
    constexpr int SOUT3 = SOUT * SOUT * SOUT;
    constexpr int CIL = CI / CI_SPLIT;
    constexpr int NW = 27 * CIL * CO_T;
    constexpr bool ATOMIC = (CI_SPLIT > 1);
    __shared__ __align__(16) float wlds[NW];
    const int cog = blockIdx.y / CI_SPLIT;
    const int cs  = blockIdx.y % CI_SPLIT;
    const int cobase = cog * CO_T;
    const int cibase = cs * CIL;
    const int b = blockIdx.z;
    for (int idx = threadIdx.x; idx < NW; idx += 256) {
        int w   = idx / (CIL * CO_T);
        int rem = idx - w * (CIL * CO_T);
        int ci  = rem / CO_T;
        int co  = rem - ci * CO_T;
        wlds[idx] = W[(size_t)(w * CI + cibase + ci) * CO + cobase + co];
    }
    __syncthreads();
    constexpr int XCH = SOUT / SP_T;
    int chunk = blockIdx.x * 256 + threadIdx.x;
    if (chunk >= SOUT * SOUT * XCH) return;
    int x0 = (chunk % XCH) * SP_T;
    int r = chunk / XCH;
    int y = r % SOUT, z = r / SOUT;

    float acc[SP_T][CO_T];
    #pragma unroll
    for (int sp = 0; sp < SP_T; ++sp)
    #pragma unroll
    for (int co = 0; co < CO_T; ++co) acc[sp][co] = 0.f;

    const float* bi = in + (size_t)(b * CI + cibase) * SIN3;
    const float* bm = MASK_IN ? (inm + (size_t)b * SIN3) : nullptr;
    const int xb0 = 2 * x0 - 1;

    #pragma unroll
    for (int kz = 0; kz < 3; ++kz) {
        int iz = 2 * z - 1 + kz;
        #pragma unroll
        for (int ky = 0; ky < 3; ++ky) {
            int iy = 2 * y - 1 + ky;
            bool rv = (iz >= 0) && (iy >= 0);
            int rowoff = (iz * SIN + iy) * SIN;
            float mrow[2 * SP_T + 1];
            if (MASK_IN) {
                #pragma unroll
                for (int t = 0; t < 2 * SP_T + 1; ++t) {
                    int ix = xb0 + t;
                    mrow[t] = (rv && ix >= 0) ? bm[rowoff + ix] : 0.f;
                }
            }
            const float* wrow = &wlds[(kz * 3 + ky) * 3 * CIL * CO_T];
            #pragma unroll 1
            for (int ci = 0; ci < CIL; ++ci) {
                const float* rp = bi + (size_t)ci * SIN3 + rowoff;
                float vx[2 * SP_T + 1];
                #pragma unroll
                for (int t = 0; t < 2 * SP_T + 1; ++t) {
                    int ix = xb0 + t;
                    float vv = (rv && ix >= 0) ? rp[ix] : 0.f;
                    if (MASK_IN) vv *= mrow[t];
                    vx[t] = vv;
                }
                const float* wp = wrow + ci * CO_T;
                #pragma unroll
                for (int kx = 0; kx < 3; ++kx)
                #pragma unroll
                for (int sp = 0; sp < SP_T; ++sp)
                #pragma unroll
                for (int co = 0; co < CO_T; ++co)
                    acc[sp][co] += vx[2 * sp + kx] * wp[kx * CIL * CO_T + co];
            }
        }
    }

    int srow = (z * SOUT + y) * SOUT + x0;
    float mm[SP_T];
    load_vec<SP_T>(mm, mout + (size_t)b * SOUT3 + srow);
    #pragma unroll
    for (int co = 0; co < CO_T; ++co) {
        float* op = out + (size_t)(b * CO + cobase + co) * SOUT3 + srow;
        if constexpr (ATOMIC) {
            #pragma unroll
            for (int sp = 0; sp < SP_T; ++sp) atomicAdd(op + sp, acc[sp][co] * mm[sp]);
        } else {
            float tmp[SP_T];
            #pragma unroll
            for (int sp = 0; sp < SP_T; ++sp) tmp[sp] = acc[sp][co] * mm[sp];
            store_vec<SP_T>(op, tmp);
        }
    }
}

// ---------------- blocked transposed conv 3x3x3 s2, output GATED by mout ------
// FINAL: fuse sigmoid*mask (d0) + occupancy head p1.
template<int CI, int CO, int CO_T, int CO_P, int SP_T, int SIN, bool FINAL, int CI_SPLIT>
__global__ __launch_bounds__(256)
void k_deconv(const float* __restrict__ in, const float* __restrict__ W,
              const float* __restrict__ mout, float* __restrict__ out,
              const float* __restrict__ occw, const float* __restrict__ occb,
              float* __restrict__ occout) {
    constexpr int SOUT = 2 * SIN;
    constexpr int SIN3 = SIN * SIN * SIN;
    constexpr int SOUT3 = SOUT * SOUT * SOUT;
    constexpr int CIL = CI / CI_SPLIT;
    constexpr int NW = 27 * CIL * CO_P;
    constexpr bool ATOMIC = (CI_SPLIT > 1);
    __shared__ __align__(16) float wlds[NW];
    const int cog = blockIdx.y / CI_SPLIT;
    const int cs  = blockIdx.y % CI_SPLIT;
    const int cobase = cog * CO_T;
    const int cibase = cs * CIL;
    const int b = blockIdx.z;
    for (int idx = threadIdx.x; idx < NW; idx += 256) {
        int w   = idx / (CIL * CO_P);
        int rem = idx - w * (CIL * CO_P);
        int ci  = rem / CO_P;
        int co  = rem - ci * CO_P;
        wlds[idx] = (co < CO_T) ? W[(size_t)(w * CI + cibase + ci) * CO + cobase + co] : 0.f;
    }
    __syncthreads();
    constexpr int KCH = SIN / SP_T;
    int chunk = blockIdx.x * 256 + threadIdx.x;
    if (chunk >= SIN * SIN * KCH) return;
    int k0 = (chunk % KCH) * SP_T;
    int r = chunk / KCH;
    int j = r % SIN, i = r / SIN;

    float acc[2][2][2 * SP_T][CO_T];
    #pragma unroll
    for (int pz = 0; pz < 2; ++pz)
    #pragma unroll
    for (int py = 0; py < 2; ++py)
    #pragma unroll
    for (int ox = 0; ox < 2 * SP_T; ++ox)
    #pragma unroll
    for (int co = 0; co < CO_T; ++co) acc[pz][py][ox][co] = 0.f;

    constexpr int PPa[3] = {1, 0, 1};   // weight idx -> output parity
    constexpr int DDa[3] = {1, 0, 0};   // weight idx -> input offset

    #pragma unroll 1
    for (int ci = 0; ci < CIL; ++ci) {
        const float* bi = in + (size_t)(b * CI + cibase + ci) * SIN3;
        float v[2][2][SP_T + 1];
        #pragma unroll
        for (int dz = 0; dz < 2; ++dz)
        #pragma unroll
        for (int dy = 0; dy < 2; ++dy) {
            int zi = i + dz, yj = j + dy;
            bool rv = (zi < SIN) && (yj < SIN);
            const float* rp = bi + (zi * SIN + yj) * SIN + k0;
            #pragma unroll
            for (int t = 0; t <= SP_T; ++t)
                v[dz][dy][t] = (rv && (k0 + t < SIN)) ? rp[t] : 0.f;
        }
        #pragma unroll
        for (int w = 0; w < 27; ++w) {
            const int wz = w / 9, wy = (w / 3) % 3, wx = w % 3;
            float wv[CO_P];
            load_vec<CO_P>(wv, &wlds[(w * CIL + ci) * CO_P]);
            #pragma unroll
            for (int sp = 0; sp < SP_T; ++sp) {
                float iv = v[DDa[wz]][DDa[wy]][sp + DDa[wx]];
                #pragma unroll
                for (int co = 0; co < CO_T; ++co)
                    acc[PPa[wz]][PPa[wy]][2 * sp + PPa[wx]][co] += iv * wv[co];
            }
        }
    }

    if constexpr (!FINAL) {
        #pragma unroll
        for (int pz = 0; pz < 2; ++pz)
        #pragma unroll
        for (int py = 0; py < 2; ++py) {
            const int row = ((2 * i + pz) * SOUT + (2 * j + py)) * SOUT + 2 * k0;
            float mm[2 * SP_T];
            load_vec<2 * SP_T>(mm, mout + (size_t)b * SOUT3 + row);
            #pragma unroll
            for (int co = 0; co < CO_T; ++co) {
                float* op = out + (size_t)(b * CO + cobase + co) * SOUT3 + row;
                if constexpr (ATOMIC) {
                    #pragma unroll
                    for (int ox = 0; ox < 2 * SP_T; ++ox) atomicAdd(op + ox, acc[pz][py][ox][co] * mm[ox]);
                } else {
                    float tmp[2 * SP_T];
                    #pragma unroll
                    for (int ox = 0; ox < 2 * SP_T; ++ox) tmp[ox] = acc[pz][py][ox][co] * mm[ox];
                    store_vec<2 * SP_T>(op, tmp);
                }
            }
        }
    } else {
        const float w0 = occw[0], w1 = occw[1], w2 = occw[2], bo = occb[0];
        #pragma unroll
        for (int pz = 0; pz < 2; ++pz)
        #pragma unroll
        for (int py = 0; py < 2; ++py) {
            const int row = ((2 * i + pz) * SOUT + (2 * j + py)) * SOUT + 2 * k0;
            float mm[2 * SP_T];
            load_vec<2 * SP_T>(mm, mout + (size_t)b * SOUT3 + row);
            float d0[3][2 * SP_T];
            float p1[2 * SP_T];
            #pragma unroll
            for (int ox = 0; ox < 2 * SP_T; ++ox) {
                float y0 = sigmoidf_(acc[pz][py][ox][0]) * mm[ox];
                float y1 = sigmoidf_(acc[pz][py][ox][1]) * mm[ox];
                float y2 = sigmoidf_(acc[pz][py][ox][2]) * mm[ox];
                d0[0][ox] = y0; d0[1][ox] = y1; d0[2][ox] = y2;
                p1[ox] = sigmoidf_(y0 * w0 + y1 * w1 + y2 * w2 + bo) * mm[ox];
            }
            #pragma unroll
            for (int co = 0; co < 3; ++co)
                store_vec<2 * SP_T>(out + (size_t)(b * 3 + co) * SOUT3 + row, d0[co]);
            store_vec<2 * SP_T>(occout + (size_t)b * SOUT3 + row, p1);
        }
    }
}

// ---------------- BN statistics on GATED x (no mask needed), float4 -----------
__global__ __launch_bounds__(256)
void k_stats(const float* __restrict__ x, int C, int S3, int NB,
             float* __restrict__ stats) {
    int c = blockIdx.y;
    int q = blockIdx.x * 256 + threadIdx.x;
    float s1 = 0.f, s2 = 0.f;
    if (q < S3 / 4) {
        for (int b = 0; b < NB; ++b) {
            float4 xv = *reinterpret_cast<const float4*>(x + ((size_t)(b * C + c)) * S3 + q * 4);
            s1 += xv.x + xv.y + xv.z + xv.w;
            s2 += xv.x * xv.x + xv.y * xv.y + xv.z * xv.z + xv.w * xv.w;
        }
    }
    for (int off = 1; off < 64; off <<= 1) {
        s1 += __shfl_xor(s1, off);
        s2 += __shfl_xor(s2, off);
    }
    __shared__ float r[8];
    int lane = threadIdx.x & 63, wid = threadIdx.x >> 6;
    if (lane == 0) { r[wid] = s1; r[4 + wid] = s2; }
    __syncthreads();
    if (threadIdx.x == 0)  atomicAdd(&stats[c],       r[0] + r[1] + r[2] + r[3]);
    if (threadIdx.x == 64) atomicAdd(&stats[128 + c], r[4] + r[5] + r[6] + r[7]);
}

// scale/shift: st[256+c]=gamma*rsqrt(var+eps), st[384+c]=beta-mean*scale
__global__ void k_finalize(float* __restrict__ st, const float* __restrict__ cnt,
                           const float* __restrict__ g, const float* __restrict__ be, int C) {
    int c = threadIdx.x;
    if (c < C) {
        float cn = *cnt;
        float mean = st[c] / cn;
        float var = st[128 + c] / cn - mean * mean;
        float sc = g[c] * rsqrtf(var + 1e-5f);
        st[256 + c] = sc;
        st[384 + c] = be[c] - mean * sc;
    }
}

// ---------------- BN apply + ReLU + mask (+ occ head, + skip add), float4 ------
template<int C, int S3, bool OCC, bool ADD>
__global__ __launch_bounds__(256)
void k_bn(float* __restrict__ x, const float* __restrict__ m,
          const float* __restrict__ st, const float* __restrict__ skip,
          const float* __restrict__ ow, const float* __restrict__ ob,
          float* __restrict__ oo, int nq) {
    int idx = blockIdx.x * 256 + threadIdx.x;
    if (idx >= nq) return;
    constexpr int SQ = S3 / 4;
    int b = idx / SQ;
    int sp = (idx - b * SQ) * 4;
    float4 mm = *reinterpret_cast<const float4*>(m + (size_t)b * S3 + sp);
    float o0 = 0.f, o1 = 0.f, o2 = 0.f, o3 = 0.f;
    #pragma unroll 4
    for (int c = 0; c < C; ++c) {
        size_t off = (size_t)(b * C + c) * S3 + sp;
        float4 xv = *reinterpret_cast<const float4*>(x + off);
        float sc = st[256 + c], sh = st[384 + c];
        float y0 = fmaxf(xv.x * sc + sh, 0.f) * mm.x;
        float y1 = fmaxf(xv.y * sc + sh, 0.f) * mm.y;
        float y2 = fmaxf(xv.z * sc + sh, 0.f) * mm.z;
        float y3 = fmaxf(xv.w * sc + sh, 0.f) * mm.w;
        if (OCC) { float wv = ow[c]; o0 += y0 * wv; o1 += y1 * wv; o2 += y2 * wv; o3 += y3 * wv; }
        if (ADD) {
            float4 sk = *reinterpret_cast<const float4*>(skip + off);
            y0 += sk.x; y1 += sk.y; y2 += sk.z; y3 += sk.w;
        }
        *reinterpret_cast<float4*>(x + off) = make_float4(y0, y1, y2, y3);
    }
    if (OCC) {
        float bb = ob[0];
        *reinterpret_cast<float4*>(oo + (size_t)b * S3 + sp) =
            make_float4(sigmoidf_(o0 + bb) * mm.x, sigmoidf_(o1 + bb) * mm.y,
                        sigmoidf_(o2 + bb) * mm.z, sigmoidf_(o3 + bb) * mm.w);
    }
}

// ---------------- launch ----------------
extern "C" void kernel_launch(void* const* d_in, const int* in_sizes, int n_in,
                              void* d_out, int out_size, void* d_ws, size_t ws_size,
                              hipStream_t stream) {
    (void)in_sizes; (void)n_in; (void)out_size; (void)ws_size;
    const float* feats = (const float*)d_in[0];
    const void*  mraw  = d_in[1];
    const float* W1 = (const float*)d_in[2];
    const float* g1 = (const float*)d_in[3];  const float* b1 = (const float*)d_in[4];
    const float* W2 = (const float*)d_in[5];
    const float* g2 = (const float*)d_in[6];  const float* b2 = (const float*)d_in[7];
    const float* W3 = (const float*)d_in[8];
    const float* g3 = (const float*)d_in[9];  const float* b3 = (const float*)d_in[10];
    const float* W4 = (const float*)d_in[11];
    const float* g4 = (const float*)d_in[12]; const float* b4 = (const float*)d_in[13];
    const float* Wt4 = (const float*)d_in[14];
    const float* gd4 = (const float*)d_in[15]; const float* bd4 = (const float*)d_in[16];
    const float* wo4 = (const float*)d_in[17]; const float* bo4 = (const float*)d_in[18];
    const float* Wt3 = (const float*)d_in[19];
    const float* gd3 = (const float*)d_in[20]; const float* bd3 = (const float*)d_in[21];
    const float* wo3 = (const float*)d_in[22]; const float* bo3 = (const float*)d_in[23];
    const float* Wt2 = (const float*)d_in[24];
    const float* gd2 = (const float*)d_in[25]; const float* bd2 = (const float*)d_in[26];
    const float* wo2 = (const float*)d_in[27]; const float* bo2 = (const float*)d_in[28];
    const float* Wt1 = (const float*)d_in[29];
    const float* wo1 = (const float*)d_in[30]; const float* bo1 = (const float*)d_in[31];

    float* out = (float*)d_out;

    const int NB = 2;
    const int V0 = 96 * 96 * 96;
    const int V1 = 48 * 48 * 48;
    const int V2 = 24 * 24 * 24;
    const int V3 = 12 * 12 * 12;
    const int V4 = 6 * 6 * 6;

    const size_t OFF_P4 = (size_t)NB * 3 * V0;
    const size_t OFF_P3 = OFF_P4 + (size_t)NB * V3;
    const size_t OFF_P2 = OFF_P3 + (size_t)NB * V2;
    const size_t OFF_P1 = OFF_P2 + (size_t)NB * V1;

    float* ws = (float*)d_ws;
    size_t o = 0;
    auto alloc = [&](size_t n) { float* p = ws + o; o += ((n + 63) / 64) * 64; return p; };
    u32*   flag  = (u32*)alloc(64);
    float* m0f   = alloc((size_t)NB * V0);
    float* m1f   = alloc((size_t)NB * V1);
    float* m2f   = alloc((size_t)NB * V2);
    float* m3f   = alloc((size_t)NB * V3);
    float* m4f   = alloc((size_t)NB * V4);
    float* cnt   = alloc(16);
    float* stats = alloc(8 * 512);
    float* e0    = alloc((size_t)NB * 16 * V1);
    float* e1    = alloc((size_t)NB * 32 * V2);
    float* e2    = alloc((size_t)NB * 64 * V3);
    float* e3    = alloc((size_t)NB * 128 * V4);
    float* d3    = alloc((size_t)NB * 64 * V3);
    float* d2    = alloc((size_t)NB * 32 * V2);
    float* d1    = alloc((size_t)NB * 16 * V1);
    (void)alloc(140000);   // guard slack

    const int T = 256;

    hipMemsetAsync(flag, 0, 256, stream);
    hipMemsetAsync(cnt, 0, 64, stream);
    hipMemsetAsync(stats, 0, 8 * 512 * sizeof(float), stream);
    // zero targets of atomic (CI-split) conv/deconv
    hipMemsetAsync(e2, 0, (size_t)NB * 64 * V3 * sizeof(float), stream);
    hipMemsetAsync(e3, 0, (size_t)NB * 128 * V4 * sizeof(float), stream);
    hipMemsetAsync(d3, 0, (size_t)NB * 64 * V3 * sizeof(float), stream);
    hipMemsetAsync(d2, 0, (size_t)NB * 32 * V2 * sizeof(float), stream);

    // masks
    k_detect<<<256, T, 0, stream>>>((const u32*)mraw, (NB * V0) / 4, flag);
    k_expand<<<CDIV(NB * V0, T), T, 0, stream>>>(mraw, flag, m0f, NB * V0);
    k_pool<<<CDIV(NB * V1, T), T, 0, stream>>>(m0f, m1f, &cnt[0], 96, NB * V1);
    k_pool<<<CDIV(NB * V2, T), T, 0, stream>>>(m1f, m2f, &cnt[1], 48, NB * V2);
    k_pool<<<CDIV(NB * V3, T), T, 0, stream>>>(m2f, m3f, &cnt[2], 24, NB * V3);
    k_pool<<<CDIV(NB * V4, T), T, 0, stream>>>(m3f, m4f, &cnt[3], 12, NB * V4);

    // ---- encoder ----
    // conv1: 96->48, 3->16, CO_T=8 x2 groups, SP_T=2 -> grid 864 blocks
    k_conv<3, 16, 8, 2, 96, 48, true, 1><<<dim3(216, 2, 2), T, 0, stream>>>(
        feats, m0f, W1, e0, m1f);
    k_stats<<<dim3(108, 16), T, 0, stream>>>(e0, 16, V1, NB, stats + 0 * 512);
    k_finalize<<<1, 128, 0, stream>>>(stats + 0 * 512, &cnt[0], g1, b1, 16);
    k_bn<16, 110592, false, false><<<216, T, 0, stream>>>(
        e0, m1f, stats + 0 * 512, nullptr, nullptr, nullptr, nullptr, NB * V1 / 4);

    // conv2: 48->24, 16->32, CO_T=8 x4 groups, SP_T=1 -> 432 blocks
    k_conv<16, 32, 8, 1, 48, 24, false, 1><<<dim3(54, 4, 2), T, 0, stream>>>(
        e0, nullptr, W2, e1, m2f);
    k_stats<<<dim3(14, 32), T, 0, stream>>>(e1, 32, V2, NB, stats + 1 * 512);
    k_finalize<<<1, 128, 0, stream>>>(stats + 1 * 512, &cnt[1], g2, b2, 32);
    k_bn<32, 13824, false, false><<<27, T, 0, stream>>>(
        e1, m2f, stats + 1 * 512, nullptr, nullptr, nullptr, nullptr, NB * V2 / 4);

    // conv3: 24->12, 32->64, CO_T=4 x16 groups x CI_SPLIT=2 -> 448 blocks
    k_conv<32, 64, 4, 1, 24, 12, false, 2><<<dim3(7, 32, 2), T, 0, stream>>>(
        e1, nullptr, W3, e2, m3f);
    k_stats<<<dim3(2, 64), T, 0, stream>>>(e2, 64, V3, NB, stats + 2 * 512);
    k_finalize<<<1, 128, 0, stream>>>(stats + 2 * 512, &cnt[2], g3, b3, 64);
    k_bn<64, 1728, false, false><<<4, T, 0, stream>>>(
        e2, m3f, stats + 2 * 512, nullptr, nullptr, nullptr, nullptr, NB * V3 / 4);

    // conv4: 12->6, 64->128, CO_T=4 x32 groups x CI_SPLIT=4 -> 256 blocks
    k_conv<64, 128, 4, 1, 12, 6, false, 4><<<dim3(1, 128, 2), T, 0, stream>>>(
        e2, nullptr, W4, e3, m4f);
    k_stats<<<dim3(1, 128), T, 0, stream>>>(e3, 128, V4, NB, stats + 3 * 512);
    k_finalize<<<1, 128, 0, stream>>>(stats + 3 * 512, &cnt[3], g4, b4, 128);
    k_bn<128, 216, false, false><<<1, T, 0, stream>>>(
        e3, m4f, stats + 3 * 512, nullptr, nullptr, nullptr, nullptr, NB * V4 / 4);

    // ---- decoder 4 -> 3 ----
    k_deconv<128, 64, 4, 4, 1, 6, false, 8><<<dim3(1, 128, 2), T, 0, stream>>>(
        e3, Wt4, m3f, d3, nullptr, nullptr, nullptr);
    k_stats<<<dim3(2, 64), T, 0, stream>>>(d3, 64, V3, NB, stats + 4 * 512);
    k_finalize<<<1, 128, 0, stream>>>(stats + 4 * 512, &cnt[2], gd4, bd4, 64);
    k_bn<64, 1728, true, true><<<4, T, 0, stream>>>(
        d3, m3f, stats + 4 * 512, e2, wo4, bo4, out + OFF_P4, NB * V3 / 4);

    // ---- decoder 3 -> 2 ----
    k_deconv<64, 32, 4, 4, 1, 12, false, 4><<<dim3(7, 32, 2), T, 0, stream>>>(
        d3, Wt3, m2f, d2, nullptr, nullptr, nullptr);
    k_stats<<<dim3(14, 32), T, 0, stream>>>(d2, 32, V2, NB, stats + 5 * 512);
    k_finalize<<<1, 128, 0, stream>>>(stats + 5 * 512, &cnt[1], gd3, bd3, 32);
    k_bn<32, 13824, true, true><<<27, T, 0, stream>>>(
        d2, m2f, stats + 5 * 512, e1, wo3, bo3, out + OFF_P3, NB * V2 / 4);

    // ---- decoder 2 -> 1 ----
    k_deconv<32, 16, 4, 4, 1, 24, false, 1><<<dim3(54, 4, 2), T, 0, stream>>>(
        d2, Wt2, m1f, d1, nullptr, nullptr, nullptr);
    k_stats<<<dim3(108, 16), T, 0, stream>>>(d1, 16, V1, NB, stats + 6 * 512);
    k_finalize<<<1, 128, 0, stream>>>(stats + 6 * 512, &cnt[0], gd2, bd2, 16);
    k_bn<16, 110592, true, true><<<216, T, 0, stream>>>(
        d1, m1f, stats + 6 * 512, e0, wo2, bo2, out + OFF_P2, NB * V1 / 4);

    // ---- final level 1 -> 0: d0 + p1 fused ----
    k_deconv<16, 3, 3, 4, 2, 48, true, 1><<<dim3(216, 1, 2), T, 0, stream>>>(
        d1, Wt1, m0f, out, wo1, bo1, out + OFF_P1);
}